// Round 2
// baseline (43.055 us; speedup 1.0000x reference)
//
#include <hip/hip_runtime.h>
#include <hip/hip_cooperative_groups.h>

namespace cg = cooperative_groups;

// GaussianEmbedding margin loss, single cooperative kernel.
//   kl(b,w,±) = 0.5 * sum_e [ s1/s2 + (m2-m1)^2/s2 - 1 + log(s2) - log(s1) ]
//   loss = mean_b sum_w max(0, MARGIN - kl_pos + kl_neg)
//
// 256 blocks x 256 threads = 1024 waves; wave <-> batch element b.
// Each lane owns 2 consecutive elements (float2, coalesced 512B row reads).
// All gather loads issued up front (one exposed HBM/L3 latency per wave).
// partial[b] -> grid.sync() -> block 0 deterministic reduction -> mean.

constexpr int E = 128;
constexpr int W = 5;
constexpr int NB = 1024;               // B
constexpr float MARGIN = 0.1f;
constexpr float LN2 = 0.69314718055994530942f;

__global__ __launch_bounds__(256) void gauss_emb_fused(
    const float* __restrict__ mu, const float* __restrict__ sigma,
    const int* __restrict__ target, const int* __restrict__ cpos,
    const int* __restrict__ cneg, float* __restrict__ partial,
    float* __restrict__ out)
{
    const int wave = threadIdx.x >> 6;
    const int lane = threadIdx.x & 63;      // lane handles elems 2*lane, 2*lane+1
    const int b = blockIdx.x * 4 + wave;

    {
        const int t = target[b];             // target is [B,1]
        const float2 m1 = ((const float2*)(mu    + (size_t)t * E))[lane];
        const float2 s1 = ((const float2*)(sigma + (size_t)t * E))[lane];

        int idx[2 * W];
#pragma unroll
        for (int k = 0; k < W; ++k) idx[k]     = cpos[b * W + k];
#pragma unroll
        for (int k = 0; k < W; ++k) idx[W + k] = cneg[b * W + k];

        // Issue all gather loads before any compute (latency overlap).
        float2 m2[2 * W], s2[2 * W];
#pragma unroll
        for (int k = 0; k < 2 * W; ++k) {
            m2[k] = ((const float2*)(mu    + (size_t)idx[k] * E))[lane];
            s2[k] = ((const float2*)(sigma + (size_t)idx[k] * E))[lane];
        }

        const float l1x = __log2f(s1.x);
        const float l1y = __log2f(s1.y);

        float kl[2 * W];
#pragma unroll
        for (int k = 0; k < 2 * W; ++k) {
            const float dx = m2[k].x - m1.x;
            const float dy = m2[k].y - m1.y;
            const float cx = (s1.x + dx * dx) / s2[k].x + LN2 * (__log2f(s2[k].x) - l1x);
            const float cy = (s1.y + dy * dy) / s2[k].y + LN2 * (__log2f(s2[k].y) - l1y);
            kl[k] = cx + cy - 2.0f;          // 2 elems per lane -> "-1" twice
        }

        // Butterfly reduce each of the 10 KL sums across the wave.
#pragma unroll
        for (int k = 0; k < 2 * W; ++k) {
#pragma unroll
            for (int off = 32; off >= 1; off >>= 1)
                kl[k] += __shfl_xor(kl[k], off, 64);
        }

        if (lane == 0) {
            float h = 0.f;
#pragma unroll
            for (int w = 0; w < W; ++w)
                h += fmaxf(0.f, MARGIN - 0.5f * kl[w] + 0.5f * kl[W + w]);
            partial[b] = h;
        }
    }

    cg::this_grid().sync();                  // device-scope visibility of partial[]

    if (blockIdx.x == 0) {
        const int t = threadIdx.x;           // 0..255
        float s = partial[t] + partial[t + 256] + partial[t + 512] + partial[t + 768];
#pragma unroll
        for (int off = 32; off >= 1; off >>= 1)
            s += __shfl_xor(s, off, 64);
        __shared__ float wave_sums[4];
        if ((t & 63) == 0) wave_sums[t >> 6] = s;
        __syncthreads();
        if (t == 0) {
            const float tot = wave_sums[0] + wave_sums[1] + wave_sums[2] + wave_sums[3];
            out[0] = tot * (1.0f / (float)NB);
        }
    }
}

extern "C" void kernel_launch(void* const* d_in, const int* in_sizes, int n_in,
                              void* d_out, int out_size, void* d_ws, size_t ws_size,
                              hipStream_t stream)
{
    const float* mu     = (const float*)d_in[0];
    const float* sigma  = (const float*)d_in[1];
    const int*   target = (const int*)d_in[2];
    const int*   cpos   = (const int*)d_in[3];
    const int*   cneg   = (const int*)d_in[4];
    float* partial = (float*)d_ws;           // 1024 floats of scratch
    float* out     = (float*)d_out;

    void* args[] = { (void*)&mu, (void*)&sigma, (void*)&target,
                     (void*)&cpos, (void*)&cneg, (void*)&partial, (void*)&out };
    hipLaunchCooperativeKernel((const void*)gauss_emb_fused,
                               dim3(NB / 4), dim3(256), args, 0, stream);
}

// Round 3
// 11.384 us; speedup vs baseline: 3.7820x; 3.7820x over previous
//
#include <hip/hip_runtime.h>

// GaussianEmbedding margin loss, two-kernel (coop launch measured 3.5x worse).
//
// Algebra: loss_w = max(0, MARGIN - kl_pos + kl_neg), and in
//   kl_neg - kl_pos = 0.5 * sum_e [ (s1+dn^2)/sn + ln(sn) - (s1+dp^2)/sp - ln(sp) ]
// the -1, -ln(s1) terms cancel. So per element only a SIGNED
//   (s1 + d^2)*rcp(s2) + ln(s2)
// survives (sign=-1 for pos, +1 for neg).
//
// Kernel 1: one wave per b. Lanes 0-31 handle the pos row of each w,
// lanes 32-63 the neg row; each lane owns 4 consecutive elems (float4).
// 12 float4 gathers per wave; one 64-lane butterfly per w yields D_w
// directly. Hinge on lane 0 -> partial[b].
// Kernel 2: single wave, deterministic reduction of 1024 partials, /B.

constexpr int E = 128;
constexpr int W = 5;
constexpr int NB = 1024;               // B
constexpr float MARGIN = 0.1f;
constexpr float LN2 = 0.69314718055994530942f;

__global__ __launch_bounds__(64) void gauss_emb_kl(
    const float* __restrict__ mu, const float* __restrict__ sigma,
    const int* __restrict__ target, const int* __restrict__ cpos,
    const int* __restrict__ cneg, float* __restrict__ partial)
{
    const int b    = blockIdx.x;
    const int lane = threadIdx.x;          // 0..63
    const int half = lane >> 5;            // 0 = pos row, 1 = neg row
    const int sub  = lane & 31;            // elem group: 4*sub .. 4*sub+3

    const int t = target[b];               // uniform -> scalar load
    const float4 m1 = ((const float4*)(mu    + (size_t)t * E))[sub];
    const float4 s1 = ((const float4*)(sigma + (size_t)t * E))[sub];

    // Context indices (uniform per block -> scalar loads), select per half.
    int idx[W];
#pragma unroll
    for (int w = 0; w < W; ++w) {
        const int ip = cpos[b * W + w];
        const int in = cneg[b * W + w];
        idx[w] = half ? in : ip;           // v_cndmask
    }

    // Issue all gathers before any compute.
    float4 m2[W], s2[W];
#pragma unroll
    for (int w = 0; w < W; ++w) {
        m2[w] = ((const float4*)(mu    + (size_t)idx[w] * E))[sub];
        s2[w] = ((const float4*)(sigma + (size_t)idx[w] * E))[sub];
    }

    const float sign = half ? 1.0f : -1.0f;

    float dW[W];
#pragma unroll
    for (int w = 0; w < W; ++w) {
        float acc = 0.f;
#pragma unroll
        for (int j = 0; j < 4; ++j) {
            const float m1j = ((const float*)&m1)[j];
            const float s1j = ((const float*)&s1)[j];
            const float m2j = ((const float*)&m2[w])[j];
            const float s2j = ((const float*)&s2[w])[j];
            const float d   = m2j - m1j;
            acc += (s1j + d * d) * __builtin_amdgcn_rcpf(s2j)
                 + LN2 * __log2f(s2j);
        }
        dW[w] = sign * acc;
    }

    // One butterfly per w sums signed halves -> D_w = kl_neg - kl_pos.
#pragma unroll
    for (int w = 0; w < W; ++w) {
#pragma unroll
        for (int off = 32; off >= 1; off >>= 1)
            dW[w] += __shfl_xor(dW[w], off, 64);
    }

    if (lane == 0) {
        float h = 0.f;
#pragma unroll
        for (int w = 0; w < W; ++w)
            h += fmaxf(0.f, MARGIN + 0.5f * dW[w]);
        partial[b] = h;
    }
}

__global__ __launch_bounds__(64) void gauss_emb_reduce(
    const float* __restrict__ partial, float* __restrict__ out)
{
    const int lane = threadIdx.x;
    const float4* p4 = (const float4*)partial;   // 256 float4
    float s = 0.f;
#pragma unroll
    for (int k = 0; k < 4; ++k) {
        const float4 v = p4[lane + 64 * k];
        s += v.x + v.y + v.z + v.w;
    }
#pragma unroll
    for (int off = 32; off >= 1; off >>= 1)
        s += __shfl_xor(s, off, 64);
    if (lane == 0) out[0] = s * (1.0f / (float)NB);
}

extern "C" void kernel_launch(void* const* d_in, const int* in_sizes, int n_in,
                              void* d_out, int out_size, void* d_ws, size_t ws_size,
                              hipStream_t stream)
{
    const float* mu     = (const float*)d_in[0];
    const float* sigma  = (const float*)d_in[1];
    const int*   target = (const int*)d_in[2];
    const int*   cpos   = (const int*)d_in[3];
    const int*   cneg   = (const int*)d_in[4];
    float* partial = (float*)d_ws;     // 1024 floats of scratch

    gauss_emb_kl<<<NB, 64, 0, stream>>>(mu, sigma, target, cpos, cneg, partial);
    gauss_emb_reduce<<<1, 64, 0, stream>>>(partial, (float*)d_out);
}